// Round 7
// baseline (434.356 us; speedup 1.0000x reference)
//
#include <hip/hip_runtime.h>
#include <hip/hip_bf16.h>

#define IN_F   4096
#define OUT_F  11008
#define NHIGH  2752
#define NLOW   8256
#define M_TOT  4096   // B*S = 2*2048

typedef __attribute__((ext_vector_type(8))) short bf16x8;
typedef __attribute__((ext_vector_type(4))) float f32x4;
typedef __attribute__((ext_vector_type(16))) float f32x16;
typedef __attribute__((ext_vector_type(4))) float f32x4v;

__device__ __forceinline__ short f2bf(float f) {
    union { float f; unsigned u; } v; v.f = f;
    unsigned r = (v.u + 0x7fffu + ((v.u >> 16) & 1u)) >> 16;
    return (short)(r & 0xffffu);
}

__device__ __forceinline__ void async16(const void* g, const void* l) {
    __builtin_amdgcn_global_load_lds(
        (const __attribute__((address_space(1))) unsigned int*)g,
        (__attribute__((address_space(3))) unsigned int*)l, 16, 0, 0);
}

// ---------------- kernel 0: forward permutation fwd[cinv[n]] = n ----------------
__global__ void fwd_perm_kernel(const int* __restrict__ cinv, int* __restrict__ fwd) {
    int n = blockIdx.x * blockDim.x + threadIdx.x;
    if (n < OUT_F) fwd[cinv[n]] = n;
}

// ---------------- kernel 1: x f32 -> bf16 (nt loads: read-once) ----------------
__global__ void cvt_x_kernel(const float* __restrict__ x, short* __restrict__ xb) {
    const int nv = (M_TOT * IN_F) / 8;
    for (int i = blockIdx.x * blockDim.x + threadIdx.x; i < nv;
         i += gridDim.x * blockDim.x) {
        const f32x4v* p = (const f32x4v*)(x + (long)i * 8);
        f32x4v a = __builtin_nontemporal_load(p);
        f32x4v b = __builtin_nontemporal_load(p + 1);
        bf16x8 o;
        o[0] = f2bf(a[0]); o[1] = f2bf(a[1]); o[2] = f2bf(a[2]); o[3] = f2bf(a[3]);
        o[4] = f2bf(b[0]); o[5] = f2bf(b[1]); o[6] = f2bf(b[2]); o[7] = f2bf(b[3]);
        *(bf16x8*)(xb + (long)i * 8) = o;
    }
}

// ---------------- kernel 2: dequant (source-major) + scatter-permute ----------------
__global__ void dequant_kernel(const int* __restrict__ hw, const float* __restrict__ hs,
                               const int* __restrict__ lw, const float* __restrict__ s1,
                               const float* __restrict__ s2, const float* __restrict__ zp,
                               const int* __restrict__ fwd,
                               short* __restrict__ wt) {
    __shared__ short tile[64 * 66];
    const int t  = threadIdx.x;
    const int c0 = blockIdx.x * 64;
    const int k0 = blockIdx.y * 64;
    const int cl = t & 63;
    const int w  = t >> 6;

    if (c0 < NHIGH) {
        const int ci = c0 + cl;
        #pragma unroll
        for (int i = 0; i < 16; ++i) {
            const int kl = w + 4 * i;
            const int k  = k0 + kl;
            int   q   = __builtin_nontemporal_load(&hw[(long)k * NHIGH + ci]);
            float val = (float)q * hs[(k >> 7) * NHIGH + ci];
            tile[cl * 66 + kl] = f2bf(val);
        }
    } else {
        const int ci = c0 - NHIGH + cl;
        const float s2v = s2[ci];
        #pragma unroll
        for (int i = 0; i < 16; ++i) {
            const int kl = w + 4 * i;
            const int k  = k0 + kl;
            int   q   = __builtin_nontemporal_load(&lw[(long)k * NLOW + ci]);
            float val = ((float)q - zp[k]) * s1[k] * s2v;
            tile[cl * 66 + kl] = f2bf(val);
        }
    }
    __syncthreads();
    const int oc = t >> 2;
    const int kq = (t & 3) * 16;
    bf16x8 o0, o1;
    #pragma unroll
    for (int j = 0; j < 8; ++j) {
        o0[j] = tile[oc * 66 + kq + j];
        o1[j] = tile[oc * 66 + kq + 8 + j];
    }
    const int ndst = fwd[c0 + oc];
    short* dst = wt + (long)ndst * IN_F + k0 + kq;
    *(bf16x8*)dst       = o0;
    *(bf16x8*)(dst + 8) = o1;
}

// ---------------- kernel 3: 256x256 8-phase GEMM, 32x32x16 MFMA ----------------
// R4 skeleton (schedule/staging/gates identical); MFMA shape upgraded to
// v_mfma_f32_32x32x16_bf16 (ceiling 2495 vs 2176 TF, half the instruction count).
#define BM 256
#define BN 256
#define BK 64
#define KT (IN_F / BK)        // 64
#define NTIL (OUT_F / BN)     // 43
#define MTIL (M_TOT / BM)     // 16
#define NWG2 (NTIL * MTIL)    // 688 (= 8 * 86)

#define BAR()    __builtin_amdgcn_s_barrier()
#define LGKM0()  asm volatile("s_waitcnt lgkmcnt(0)" ::: "memory")
#define LGKM8()  asm volatile("s_waitcnt lgkmcnt(8)" ::: "memory")
#define VMC(N)   asm volatile("s_waitcnt vmcnt(" #N ")" ::: "memory")

__global__ __launch_bounds__(512, 2) void gemm_kernel(
    const short* __restrict__ A,    // [M_TOT][IN_F] bf16
    const short* __restrict__ Bt,   // [OUT_F][IN_F] bf16
    const float* __restrict__ bias,
    float* __restrict__ C) {
    __shared__ __align__(16) short lds_s[65536];   // 128 KiB
    char* const lds = (char*)lds_s;

    const int t    = threadIdx.x;
    const int lane = t & 63;
    const int w    = t >> 6;      // 0..7
    const int wr   = w >> 1;      // unused placeholder (kept numbering below)
    const int wrr  = w >> 2;      // 0..1  : A 128-row half
    const int wc   = w & 3;       // 0..3  : B 64-row slice

    // R4 raster: XCD-bijective swizzle + supertile (4 m-tiles per super-row)
    const int swz   = (blockIdx.x % 8) * (NWG2 / 8) + blockIdx.x / 8;
    const int sr    = swz / (4 * NTIL);
    const int in_sr = swz % (4 * NTIL);
    const int nb    = in_sr / 4;
    const int mb    = sr * 4 + (in_sr & 3);
    const int m0    = mb * BM;
    const int n0    = nb * BN;
    (void)wr;

    // staging: wave w, lane l -> row w*8 + (l>>3); source chunk (l&7)^(l>>3)
    const int srow = w * 8 + (lane >> 3);
    const int scb  = ((lane & 7) ^ (lane >> 3)) * 16;
    const char* gA0 = (const char*)A  + (long)(m0 + srow) * (IN_F * 2) + scb;
    const char* gB0 = (const char*)Bt + (long)(n0 + srow) * (IN_F * 2) + scb;

    // ds_read lane bases for 32x32x16 frags: row = base + (lane&31),
    // k-chunk ks*2+(lane>>5), swizzled ^(lane&7) (row&7 == lane&7 in 32-blocks)
    const int rlA = (lane & 31) * 128;
    int kb32[4];
    #pragma unroll
    for (int ks = 0; ks < 4; ++ks)
        kb32[ks] = ((ks * 2 + (lane >> 5)) ^ (lane & 7)) * 16;

#define STAGE(gbase, region_off, h, ktile) do {                                  \
        const char* _g = (gbase) + (long)((h) * 128) * (IN_F * 2) + (ktile) * 128; \
        char* _l = lds + (region_off) + (h) * 16384 + w * 1024;                  \
        async16(_g,                        _l);                                  \
        async16(_g + (long)64 * (IN_F * 2), _l + 8192);                          \
    } while (0)

    f32x16 acc[4][2];
    #pragma unroll
    for (int i = 0; i < 4; ++i)
        #pragma unroll
        for (int j = 0; j < 2; ++j)
            acc[i][j] = (f32x16){0.f,0.f,0.f,0.f,0.f,0.f,0.f,0.f,
                                 0.f,0.f,0.f,0.f,0.f,0.f,0.f,0.f};

    bf16x8 a[2][4], b0[4], b1[4];

// A quadrant mq (64 rows of this wave's 128): rb in {0,1} 32-row blocks, ks 0..3
#define RD_A32(buf, mq) do {                                                     \
        char* _p = lds + (buf) * 65536 + wrr * 16384 + (mq) * 8192 + rlA;        \
        _Pragma("unroll")                                                        \
        for (int _rb = 0; _rb < 2; ++_rb)                                        \
        _Pragma("unroll")                                                        \
        for (int _ks = 0; _ks < 4; ++_ks)                                        \
            a[_rb][_ks] = *(const bf16x8*)(_p + _rb * 4096 + kb32[_ks]);         \
    } while (0)

// B quadrant nq (32 rows of this wave's 64): ks 0..3
#define RD_B32(buf, nq, breg) do {                                               \
        char* _p = lds + (buf) * 65536 + 32768 + wc * 8192 + (nq) * 4096 + rlA;  \
        _Pragma("unroll")                                                        \
        for (int _ks = 0; _ks < 4; ++_ks)                                        \
            breg[_ks] = *(const bf16x8*)(_p + kb32[_ks]);                        \
    } while (0)

// 8 MFMA: k-outer, rb-inner (2 independent acc chains, cross-wave covers latency)
#define MMA_Q32(mq, nq, breg) do {                                               \
        __builtin_amdgcn_s_setprio(1);                                           \
        _Pragma("unroll")                                                        \
        for (int _ks = 0; _ks < 4; ++_ks)                                        \
        _Pragma("unroll")                                                        \
        for (int _rb = 0; _rb < 2; ++_rb)                                        \
            acc[(mq)*2+_rb][(nq)] = __builtin_amdgcn_mfma_f32_32x32x16_bf16(     \
                a[_rb][_ks], breg[_ks], acc[(mq)*2+_rb][(nq)], 0, 0, 0);         \
        __builtin_amdgcn_s_setprio(0);                                           \
    } while (0)

    // prologue: buf0 = tile 0 (4 halves), buf1.A h0 = tile 1
    STAGE(gA0, 0,     0, 0);
    STAGE(gA0, 0,     1, 0);
    STAGE(gB0, 32768, 0, 0);
    STAGE(gB0, 32768, 1, 0);
    STAGE(gA0, 65536, 0, 1);
    VMC(2);
    BAR();

    #pragma unroll 1
    for (int it = 0; it < KT / 2; ++it) {
        const int kt1 = 2 * it + 1;
        const int kt2 = (2 * it + 2 < KT) ? 2 * it + 2 : KT - 1;
        const int kt3 = (2 * it + 3 < KT) ? 2 * it + 3 : KT - 1;

        // ---- K-tile 2it (buf0) ----
        RD_A32(0, 0); RD_B32(0, 0, b0);
        STAGE(gA0, 65536 + 0,     1, kt1);
        LGKM8();
        BAR(); LGKM0();
        MMA_Q32(0, 0, b0);
        BAR();

        RD_B32(0, 1, b1);
        STAGE(gB0, 65536 + 32768, 0, kt1);
        BAR(); LGKM0();
        MMA_Q32(0, 1, b1);
        BAR();

        RD_A32(0, 1);
        STAGE(gB0, 65536 + 32768, 1, kt1);
        BAR(); LGKM0();
        MMA_Q32(1, 1, b1);
        BAR();

        STAGE(gA0, 0,             0, kt2);
        BAR();
        MMA_Q32(1, 0, b0);
        VMC(2);
        BAR();

        // ---- K-tile 2it+1 (buf1) ----
        RD_A32(1, 0); RD_B32(1, 0, b0);
        STAGE(gA0, 0,             1, kt2);
        LGKM8();
        BAR(); LGKM0();
        MMA_Q32(0, 0, b0);
        BAR();

        RD_B32(1, 1, b1);
        STAGE(gB0, 32768,         0, kt2);
        BAR(); LGKM0();
        MMA_Q32(0, 1, b1);
        BAR();

        RD_A32(1, 1);
        STAGE(gB0, 32768,         1, kt2);
        BAR(); LGKM0();
        MMA_Q32(1, 1, b1);
        BAR();

        STAGE(gA0, 65536,         0, kt3);
        BAR();
        MMA_Q32(1, 0, b0);
        VMC(2);
        BAR();
    }

    asm volatile("s_waitcnt vmcnt(0)" ::: "memory");

    // epilogue: 32x32 C/D layout — col = lane&31, row = (reg&3)+8*(reg>>2)+4*(lane>>5)
    #pragma unroll
    for (int fn = 0; fn < 2; ++fn) {
        const int ec = n0 + wc * 64 + fn * 32 + (lane & 31);
        const float bv = bias[ec];
        #pragma unroll
        for (int fm = 0; fm < 4; ++fm) {
            const int rbase = m0 + wrr * 128 + fm * 32 + 4 * (lane >> 5);
            #pragma unroll
            for (int g = 0; g < 4; ++g) {
                #pragma unroll
                for (int q = 0; q < 4; ++q) {
                    __builtin_nontemporal_store(
                        acc[fm][fn][g * 4 + q] + bv,
                        &C[(long)(rbase + 8 * g + q) * OUT_F + ec]);
                }
            }
        }
    }
}

extern "C" void kernel_launch(void* const* d_in, const int* in_sizes, int n_in,
                              void* d_out, int out_size, void* d_ws, size_t ws_size,
                              hipStream_t stream) {
    const float* x    = (const float*)d_in[0];
    const int*   hw   = (const int*)d_in[1];
    const float* hs   = (const float*)d_in[2];
    const int*   lw   = (const int*)d_in[3];
    const float* s1   = (const float*)d_in[4];
    const float* s2   = (const float*)d_in[5];
    const float* zp   = (const float*)d_in[6];
    const int*   cinv = (const int*)d_in[7];
    const float* bias = (const float*)d_in[8];
    float*       out  = (float*)d_out;

    short* wt  = (short*)d_ws;                                     // 90,177,536 B
    short* xb  = (short*)((char*)d_ws + (size_t)OUT_F * IN_F * 2); // +33,554,432 B
    int*   fwd = (int*)((char*)d_ws + (size_t)OUT_F * IN_F * 2
                                    + (size_t)M_TOT * IN_F * 2);   // +44,032 B

    fwd_perm_kernel<<<(OUT_F + 255) / 256, 256, 0, stream>>>(cinv, fwd);
    cvt_x_kernel<<<2048, 256, 0, stream>>>(x, xb);
    dequant_kernel<<<dim3(OUT_F / 64, IN_F / 64), 256, 0, stream>>>(
        hw, hs, lw, s1, s2, zp, fwd, wt);
    gemm_kernel<<<NWG2, 512, 0, stream>>>(xb, wt, bias, out);
}

// Round 8
// 403.963 us; speedup vs baseline: 1.0752x; 1.0752x over previous
//
#include <hip/hip_runtime.h>
#include <hip/hip_bf16.h>

#define IN_F   4096
#define OUT_F  11008
#define NHIGH  2752
#define NLOW   8256
#define M_TOT  4096   // B*S = 2*2048

typedef __attribute__((ext_vector_type(8))) short bf16x8;
typedef __attribute__((ext_vector_type(4))) float f32x4;
typedef __attribute__((ext_vector_type(4))) float f32x4v;

__device__ __forceinline__ short f2bf(float f) {
    union { float f; unsigned u; } v; v.f = f;
    unsigned r = (v.u + 0x7fffu + ((v.u >> 16) & 1u)) >> 16;
    return (short)(r & 0xffffu);
}

__device__ __forceinline__ void async16(const void* g, const void* l) {
    __builtin_amdgcn_global_load_lds(
        (const __attribute__((address_space(1))) unsigned int*)g,
        (__attribute__((address_space(3))) unsigned int*)l, 16, 0, 0);
}

// ---------------- kernel 0: forward permutation fwd[cinv[n]] = n ----------------
__global__ void fwd_perm_kernel(const int* __restrict__ cinv, int* __restrict__ fwd) {
    int n = blockIdx.x * blockDim.x + threadIdx.x;
    if (n < OUT_F) fwd[cinv[n]] = n;
}

// ---------------- kernel 1: x f32 -> bf16 (nt loads: read-once) ----------------
__global__ void cvt_x_kernel(const float* __restrict__ x, short* __restrict__ xb) {
    const int nv = (M_TOT * IN_F) / 8;
    for (int i = blockIdx.x * blockDim.x + threadIdx.x; i < nv;
         i += gridDim.x * blockDim.x) {
        const f32x4v* p = (const f32x4v*)(x + (long)i * 8);
        f32x4v a = __builtin_nontemporal_load(p);
        f32x4v b = __builtin_nontemporal_load(p + 1);
        bf16x8 o;
        o[0] = f2bf(a[0]); o[1] = f2bf(a[1]); o[2] = f2bf(a[2]); o[3] = f2bf(a[3]);
        o[4] = f2bf(b[0]); o[5] = f2bf(b[1]); o[6] = f2bf(b[2]); o[7] = f2bf(b[3]);
        *(bf16x8*)(xb + (long)i * 8) = o;
    }
}

// ---------------- kernel 2: dequant (source-major) + scatter-permute ----------------
__global__ void dequant_kernel(const int* __restrict__ hw, const float* __restrict__ hs,
                               const int* __restrict__ lw, const float* __restrict__ s1,
                               const float* __restrict__ s2, const float* __restrict__ zp,
                               const int* __restrict__ fwd,
                               short* __restrict__ wt) {
    __shared__ short tile[64 * 66];
    const int t  = threadIdx.x;
    const int c0 = blockIdx.x * 64;
    const int k0 = blockIdx.y * 64;
    const int cl = t & 63;
    const int w  = t >> 6;

    if (c0 < NHIGH) {
        const int ci = c0 + cl;
        #pragma unroll
        for (int i = 0; i < 16; ++i) {
            const int kl = w + 4 * i;
            const int k  = k0 + kl;
            int   q   = __builtin_nontemporal_load(&hw[(long)k * NHIGH + ci]);
            float val = (float)q * hs[(k >> 7) * NHIGH + ci];
            tile[cl * 66 + kl] = f2bf(val);
        }
    } else {
        const int ci = c0 - NHIGH + cl;
        const float s2v = s2[ci];
        #pragma unroll
        for (int i = 0; i < 16; ++i) {
            const int kl = w + 4 * i;
            const int k  = k0 + kl;
            int   q   = __builtin_nontemporal_load(&lw[(long)k * NLOW + ci]);
            float val = ((float)q - zp[k]) * s1[k] * s2v;
            tile[cl * 66 + kl] = f2bf(val);
        }
    }
    __syncthreads();
    const int oc = t >> 2;
    const int kq = (t & 3) * 16;
    bf16x8 o0, o1;
    #pragma unroll
    for (int j = 0; j < 8; ++j) {
        o0[j] = tile[oc * 66 + kq + j];
        o1[j] = tile[oc * 66 + kq + 8 + j];
    }
    const int ndst = fwd[c0 + oc];
    short* dst = wt + (long)ndst * IN_F + k0 + kq;
    *(bf16x8*)dst       = o0;
    *(bf16x8*)(dst + 8) = o1;
}

// ---------------- kernel 3: 256x256 8-phase GEMM (R4 schedule, m-outer raster) ----------------
#define BM 256
#define BN 256
#define BK 64
#define KT (IN_F / BK)        // 64
#define NTIL (OUT_F / BN)     // 43
#define MTIL (M_TOT / BM)     // 16
#define NWG2 (NTIL * MTIL)    // 688 (= 8 * 86)

#define BAR()    __builtin_amdgcn_s_barrier()
#define LGKM0()  asm volatile("s_waitcnt lgkmcnt(0)" ::: "memory")
#define VMC(N)   asm volatile("s_waitcnt vmcnt(" #N ")" ::: "memory")

__global__ __launch_bounds__(512, 2) void gemm_kernel(
    const short* __restrict__ A,    // [M_TOT][IN_F] bf16
    const short* __restrict__ Bt,   // [OUT_F][IN_F] bf16
    const float* __restrict__ bias,
    float* __restrict__ C) {
    __shared__ __align__(16) short lds_s[65536];   // 128 KiB
    char* const lds = (char*)lds_s;

    const int t    = threadIdx.x;
    const int lane = t & 63;
    const int w    = t >> 6;      // 0..7
    const int wr   = w >> 2;      // 0..1  (M)
    const int wc   = w & 3;       // 0..3  (N)

    // XCD-bijective swizzle + M-OUTER raster: per XCD only 2 A panels (4 MB,
    // L2-resident); B streams through L2 once per mb-round, stays L3-resident.
    const int swz = (blockIdx.x % 8) * (NWG2 / 8) + blockIdx.x / 8;
    const int mb  = swz / NTIL;   // 0..15, slow
    const int nb  = swz % NTIL;   // 0..42, fast
    const int m0  = mb * BM;
    const int n0  = nb * BN;

    // staging: wave w, lane l -> half-row w*8 + (l>>3); source col-byte
    // pre-swizzled ((l&7)^(l>>3))*16
    const int srow = w * 8 + (lane >> 3);
    const int scb  = ((lane & 7) ^ (lane >> 3)) * 16;
    const char* gA0 = (const char*)A  + (long)(m0 + srow) * (IN_F * 2) + scb;
    const char* gB0 = (const char*)Bt + (long)(n0 + srow) * (IN_F * 2) + scb;

    // ds_read lane bases
    const int rl  = (lane & 15) * 128;
    const int kb0 = ((lane >> 4) * 16) ^ ((lane & 7) << 4);
    const int kb1 = kb0 ^ 64;

#define STAGE(gbase, region_off, h, ktile) do {                                  \
        const char* _g = (gbase) + (long)((h) * 128) * (IN_F * 2) + (ktile) * 128; \
        char* _l = lds + (region_off) + (h) * 16384 + w * 1024;                  \
        async16(_g,                        _l);                                  \
        async16(_g + (long)64 * (IN_F * 2), _l + 8192);                          \
    } while (0)

    f32x4 acc[8][4];
    #pragma unroll
    for (int i = 0; i < 8; ++i)
        #pragma unroll
        for (int j = 0; j < 4; ++j)
            acc[i][j] = (f32x4){0.f, 0.f, 0.f, 0.f};

    bf16x8 a[4][2], b0[2][2], b1[2][2];

#define RD_A(buf, mq) do {                                                       \
        char* _p = lds + (buf) * 65536 + wr * 16384 + (mq) * 8192 + rl;          \
        _Pragma("unroll")                                                        \
        for (int _j = 0; _j < 4; ++_j) {                                         \
            a[_j][0] = *(const bf16x8*)(_p + _j * 2048 + kb0);                   \
            a[_j][1] = *(const bf16x8*)(_p + _j * 2048 + kb1);                   \
        }                                                                        \
    } while (0)

#define RD_B(buf, nq, breg) do {                                                 \
        char* _p = lds + (buf) * 65536 + 32768 + wc * 8192 + (nq) * 4096 + rl;   \
        _Pragma("unroll")                                                        \
        for (int _n = 0; _n < 2; ++_n) {                                         \
            breg[_n][0] = *(const bf16x8*)(_p + _n * 2048 + kb0);                \
            breg[_n][1] = *(const bf16x8*)(_p + _n * 2048 + kb1);                \
        }                                                                        \
    } while (0)

#define MMA_Q(mq, nq, breg) do {                                                 \
        __builtin_amdgcn_s_setprio(1);                                           \
        _Pragma("unroll")                                                        \
        for (int _j = 0; _j < 4; ++_j)                                           \
        _Pragma("unroll")                                                        \
        for (int _n = 0; _n < 2; ++_n) {                                         \
            acc[(mq)*4+_j][(nq)*2+_n] = __builtin_amdgcn_mfma_f32_16x16x32_bf16( \
                a[_j][0], breg[_n][0], acc[(mq)*4+_j][(nq)*2+_n], 0, 0, 0);      \
            acc[(mq)*4+_j][(nq)*2+_n] = __builtin_amdgcn_mfma_f32_16x16x32_bf16( \
                a[_j][1], breg[_n][1], acc[(mq)*4+_j][(nq)*2+_n], 0, 0, 0);      \
        }                                                                        \
        __builtin_amdgcn_s_setprio(0);                                           \
    } while (0)

    // prologue: buf0 = tile 0 (4 halves), buf1.A h0 = tile 1
    STAGE(gA0, 0,     0, 0);
    STAGE(gA0, 0,     1, 0);
    STAGE(gB0, 32768, 0, 0);
    STAGE(gB0, 32768, 1, 0);
    STAGE(gA0, 65536, 0, 1);
    VMC(2);
    BAR();

    #pragma unroll 1
    for (int it = 0; it < KT / 2; ++it) {
        const int kt1 = 2 * it + 1;
        const int kt2 = (2 * it + 2 < KT) ? 2 * it + 2 : KT - 1;
        const int kt3 = (2 * it + 3 < KT) ? 2 * it + 3 : KT - 1;

        // ---- K-tile 2it (buf0) ----
        RD_A(0, 0); RD_B(0, 0, b0);
        STAGE(gA0, 65536 + 0,     1, kt1);
        BAR(); LGKM0();
        MMA_Q(0, 0, b0);
        BAR();

        RD_B(0, 1, b1);
        STAGE(gB0, 65536 + 32768, 0, kt1);
        BAR(); LGKM0();
        MMA_Q(0, 1, b1);
        BAR();

        RD_A(0, 1);
        STAGE(gB0, 65536 + 32768, 1, kt1);
        BAR(); LGKM0();
        MMA_Q(1, 1, b1);
        BAR();

        STAGE(gA0, 0,             0, kt2);
        BAR();
        MMA_Q(1, 0, b0);
        VMC(2);
        BAR();

        // ---- K-tile 2it+1 (buf1) ----
        RD_A(1, 0); RD_B(1, 0, b0);
        STAGE(gA0, 0,             1, kt2);
        BAR(); LGKM0();
        MMA_Q(0, 0, b0);
        BAR();

        RD_B(1, 1, b1);
        STAGE(gB0, 32768,         0, kt2);
        BAR(); LGKM0();
        MMA_Q(0, 1, b1);
        BAR();

        RD_A(1, 1);
        STAGE(gB0, 32768,         1, kt2);
        BAR(); LGKM0();
        MMA_Q(1, 1, b1);
        BAR();

        STAGE(gA0, 65536,         0, kt3);
        BAR();
        MMA_Q(1, 0, b0);
        VMC(2);
        BAR();
    }

    asm volatile("s_waitcnt vmcnt(0)" ::: "memory");

    // epilogue: nt stores — C write-once, keep L2/L3 for A/B
    const int er = m0 + wr * 128 + (lane >> 4) * 4;
    const int ec = n0 + wc * 64 + (lane & 15);
    #pragma unroll
    for (int ni = 0; ni < 4; ++ni) {
        const float bv = bias[ec + ni * 16];
        #pragma unroll
        for (int mi = 0; mi < 8; ++mi) {
            #pragma unroll
            for (int r = 0; r < 4; ++r) {
                __builtin_nontemporal_store(
                    acc[mi][ni][r] + bv,
                    &C[(long)(er + mi * 16 + r) * OUT_F + ec + ni * 16]);
            }
        }
    }
}

extern "C" void kernel_launch(void* const* d_in, const int* in_sizes, int n_in,
                              void* d_out, int out_size, void* d_ws, size_t ws_size,
                              hipStream_t stream) {
    const float* x    = (const float*)d_in[0];
    const int*   hw   = (const int*)d_in[1];
    const float* hs   = (const float*)d_in[2];
    const int*   lw   = (const int*)d_in[3];
    const float* s1   = (const float*)d_in[4];
    const float* s2   = (const float*)d_in[5];
    const float* zp   = (const float*)d_in[6];
    const int*   cinv = (const int*)d_in[7];
    const float* bias = (const float*)d_in[8];
    float*       out  = (float*)d_out;

    short* wt  = (short*)d_ws;                                     // 90,177,536 B
    short* xb  = (short*)((char*)d_ws + (size_t)OUT_F * IN_F * 2); // +33,554,432 B
    int*   fwd = (int*)((char*)d_ws + (size_t)OUT_F * IN_F * 2
                                    + (size_t)M_TOT * IN_F * 2);   // +44,032 B

    fwd_perm_kernel<<<(OUT_F + 255) / 256, 256, 0, stream>>>(cinv, fwd);
    cvt_x_kernel<<<2048, 256, 0, stream>>>(x, xb);
    dequant_kernel<<<dim3(OUT_F / 64, IN_F / 64), 256, 0, stream>>>(
        hw, hs, lw, s1, s2, zp, fwd, wt);
    gemm_kernel<<<NWG2, 512, 0, stream>>>(xb, wt, bias, out);
}

// Round 9
// 392.977 us; speedup vs baseline: 1.1053x; 1.0280x over previous
//
#include <hip/hip_runtime.h>
#include <hip/hip_bf16.h>

#define IN_F   4096
#define OUT_F  11008
#define NHIGH  2752
#define NLOW   8256
#define M_TOT  4096   // B*S = 2*2048

typedef __attribute__((ext_vector_type(8))) short bf16x8;
typedef __attribute__((ext_vector_type(4))) float f32x4;
typedef __attribute__((ext_vector_type(4))) float f32x4v;

__device__ __forceinline__ short f2bf(float f) {
    union { float f; unsigned u; } v; v.f = f;
    unsigned r = (v.u + 0x7fffu + ((v.u >> 16) & 1u)) >> 16;
    return (short)(r & 0xffffu);
}

__device__ __forceinline__ void async16(const void* g, const void* l) {
    __builtin_amdgcn_global_load_lds(
        (const __attribute__((address_space(1))) unsigned int*)g,
        (__attribute__((address_space(3))) unsigned int*)l, 16, 0, 0);
}

// ---------------- kernel 0: forward permutation fwd[cinv[n]] = n ----------------
__global__ void fwd_perm_kernel(const int* __restrict__ cinv, int* __restrict__ fwd) {
    int n = blockIdx.x * blockDim.x + threadIdx.x;
    if (n < OUT_F) fwd[cinv[n]] = n;
}

// ---------------- kernel 1: x f32 -> bf16 (nt loads: read-once) ----------------
__global__ void cvt_x_kernel(const float* __restrict__ x, short* __restrict__ xb) {
    const int nv = (M_TOT * IN_F) / 8;
    for (int i = blockIdx.x * blockDim.x + threadIdx.x; i < nv;
         i += gridDim.x * blockDim.x) {
        const f32x4v* p = (const f32x4v*)(x + (long)i * 8);
        f32x4v a = __builtin_nontemporal_load(p);
        f32x4v b = __builtin_nontemporal_load(p + 1);
        bf16x8 o;
        o[0] = f2bf(a[0]); o[1] = f2bf(a[1]); o[2] = f2bf(a[2]); o[3] = f2bf(a[3]);
        o[4] = f2bf(b[0]); o[5] = f2bf(b[1]); o[6] = f2bf(b[2]); o[7] = f2bf(b[3]);
        *(bf16x8*)(xb + (long)i * 8) = o;
    }
}

// ---------------- kernel 2: dequant (source-major) + scatter-permute ----------------
__global__ void dequant_kernel(const int* __restrict__ hw, const float* __restrict__ hs,
                               const int* __restrict__ lw, const float* __restrict__ s1,
                               const float* __restrict__ s2, const float* __restrict__ zp,
                               const int* __restrict__ fwd,
                               short* __restrict__ wt) {
    __shared__ short tile[64 * 66];
    const int t  = threadIdx.x;
    const int c0 = blockIdx.x * 64;
    const int k0 = blockIdx.y * 64;
    const int cl = t & 63;
    const int w  = t >> 6;

    if (c0 < NHIGH) {
        const int ci = c0 + cl;
        #pragma unroll
        for (int i = 0; i < 16; ++i) {
            const int kl = w + 4 * i;
            const int k  = k0 + kl;
            int   q   = __builtin_nontemporal_load(&hw[(long)k * NHIGH + ci]);
            float val = (float)q * hs[(k >> 7) * NHIGH + ci];
            tile[cl * 66 + kl] = f2bf(val);
        }
    } else {
        const int ci = c0 - NHIGH + cl;
        const float s2v = s2[ci];
        #pragma unroll
        for (int i = 0; i < 16; ++i) {
            const int kl = w + 4 * i;
            const int k  = k0 + kl;
            int   q   = __builtin_nontemporal_load(&lw[(long)k * NLOW + ci]);
            float val = ((float)q - zp[k]) * s1[k] * s2v;
            tile[cl * 66 + kl] = f2bf(val);
        }
    }
    __syncthreads();
    const int oc = t >> 2;
    const int kq = (t & 3) * 16;
    bf16x8 o0, o1;
    #pragma unroll
    for (int j = 0; j < 8; ++j) {
        o0[j] = tile[oc * 66 + kq + j];
        o1[j] = tile[oc * 66 + kq + 8 + j];
    }
    const int ndst = fwd[c0 + oc];
    short* dst = wt + (long)ndst * IN_F + k0 + kq;
    *(bf16x8*)dst       = o0;
    *(bf16x8*)(dst + 8) = o1;
}

// ---------------- kernel 3: 256x256 GEMM, 1-barrier-per-K-tile, counted-lgkm overlap ----------------
// Per K-tile: issue ALL 24 ds_reads -> issue 8 STAGE loads (tile T+1 into buf^1,
// no WAR with current reads) -> 4 MFMA quadrants (compiler inserts counted
// lgkmcnt before first use of each frag set -> LDS reads overlap MFMA) ->
// VMC(0) + BAR (only sync point; staging had the whole tile to land).
#define BM 256
#define BN 256
#define BK 64
#define KT (IN_F / BK)        // 64
#define NTIL (OUT_F / BN)     // 43
#define MTIL (M_TOT / BM)     // 16
#define NWG2 (NTIL * MTIL)    // 688 (= 8 * 86)

#define BAR()    __builtin_amdgcn_s_barrier()
#define VMC0()   asm volatile("s_waitcnt vmcnt(0)" ::: "memory")

__global__ __launch_bounds__(512, 2) void gemm_kernel(
    const short* __restrict__ A,    // [M_TOT][IN_F] bf16
    const short* __restrict__ Bt,   // [OUT_F][IN_F] bf16
    const float* __restrict__ bias,
    float* __restrict__ C) {
    __shared__ __align__(16) short lds_s[65536];   // 128 KiB
    char* const lds = (char*)lds_s;

    const int t    = threadIdx.x;
    const int lane = t & 63;
    const int w    = t >> 6;      // 0..7
    const int wr   = w >> 2;      // 0..1  (M)
    const int wc   = w & 3;       // 0..3  (N)

    // R4 raster: XCD-bijective swizzle + supertile (4 m-tiles per super-row)
    const int swz   = (blockIdx.x % 8) * (NWG2 / 8) + blockIdx.x / 8;
    const int sr    = swz / (4 * NTIL);
    const int in_sr = swz % (4 * NTIL);
    const int nb    = in_sr / 4;
    const int mb    = sr * 4 + (in_sr & 3);
    const int m0    = mb * BM;
    const int n0    = nb * BN;

    // staging: wave w, lane l -> half-row w*8 + (l>>3); source col-byte
    // pre-swizzled ((l&7)^(l>>3))*16
    const int srow = w * 8 + (lane >> 3);
    const int scb  = ((lane & 7) ^ (lane >> 3)) * 16;
    const char* gA0 = (const char*)A  + (long)(m0 + srow) * (IN_F * 2) + scb;
    const char* gB0 = (const char*)Bt + (long)(n0 + srow) * (IN_F * 2) + scb;

    // ds_read lane bases
    const int rl  = (lane & 15) * 128;
    const int kb0 = ((lane >> 4) * 16) ^ ((lane & 7) << 4);
    const int kb1 = kb0 ^ 64;

#define STAGE(gbase, region_off, h, ktile) do {                                  \
        const char* _g = (gbase) + (long)((h) * 128) * (IN_F * 2) + (ktile) * 128; \
        char* _l = lds + (region_off) + (h) * 16384 + w * 1024;                  \
        async16(_g,                        _l);                                  \
        async16(_g + (long)64 * (IN_F * 2), _l + 8192);                          \
    } while (0)

    f32x4 acc[8][4];
    #pragma unroll
    for (int i = 0; i < 8; ++i)
        #pragma unroll
        for (int j = 0; j < 4; ++j)
            acc[i][j] = (f32x4){0.f, 0.f, 0.f, 0.f};

    bf16x8 aA[4][2], aB[4][2], b0[2][2], b1[2][2];

#define RD_A(buf, mq, areg) do {                                                 \
        char* _p = lds + (buf) * 65536 + wr * 16384 + (mq) * 8192 + rl;          \
        _Pragma("unroll")                                                        \
        for (int _j = 0; _j < 4; ++_j) {                                         \
            areg[_j][0] = *(const bf16x8*)(_p + _j * 2048 + kb0);                \
            areg[_j][1] = *(const bf16x8*)(_p + _j * 2048 + kb1);                \
        }                                                                        \
    } while (0)

#define RD_B(buf, nq, breg) do {                                                 \
        char* _p = lds + (buf) * 65536 + 32768 + wc * 8192 + (nq) * 4096 + rl;   \
        _Pragma("unroll")                                                        \
        for (int _n = 0; _n < 2; ++_n) {                                         \
            breg[_n][0] = *(const bf16x8*)(_p + _n * 2048 + kb0);                \
            breg[_n][1] = *(const bf16x8*)(_p + _n * 2048 + kb1);                \
        }                                                                        \
    } while (0)

#define MMA_Q(mq, nq, areg, breg) do {                                           \
        __builtin_amdgcn_s_setprio(1);                                           \
        _Pragma("unroll")                                                        \
        for (int _j = 0; _j < 4; ++_j)                                           \
        _Pragma("unroll")                                                        \
        for (int _n = 0; _n < 2; ++_n) {                                         \
            acc[(mq)*4+_j][(nq)*2+_n] = __builtin_amdgcn_mfma_f32_16x16x32_bf16( \
                areg[_j][0], breg[_n][0], acc[(mq)*4+_j][(nq)*2+_n], 0, 0, 0);   \
            acc[(mq)*4+_j][(nq)*2+_n] = __builtin_amdgcn_mfma_f32_16x16x32_bf16( \
                areg[_j][1], breg[_n][1], acc[(mq)*4+_j][(nq)*2+_n], 0, 0, 0);   \
        }                                                                        \
        __builtin_amdgcn_s_setprio(0);                                           \
    } while (0)

// one K-tile: reads (consumption order) -> stage next tile -> 4 MFMA quadrants
// -> vmcnt(0) + barrier (single sync point per tile).
#define TILE_BODY(buf, ktn) do {                                                 \
        RD_A(buf, 0, aA);                                                        \
        RD_B(buf, 0, b0);                                                        \
        RD_B(buf, 1, b1);                                                        \
        RD_A(buf, 1, aB);                                                        \
        STAGE(gA0, ((buf)^1) * 65536,         0, ktn);                           \
        STAGE(gA0, ((buf)^1) * 65536,         1, ktn);                           \
        STAGE(gB0, ((buf)^1) * 65536 + 32768, 0, ktn);                           \
        STAGE(gB0, ((buf)^1) * 65536 + 32768, 1, ktn);                           \
        MMA_Q(0, 0, aA, b0);                                                     \
        MMA_Q(0, 1, aA, b1);                                                     \
        MMA_Q(1, 1, aB, b1);                                                     \
        MMA_Q(1, 0, aB, b0);                                                     \
        VMC0(); BAR();                                                           \
    } while (0)

    // prologue: stage tile 0 into buf0
    STAGE(gA0, 0,     0, 0);
    STAGE(gA0, 0,     1, 0);
    STAGE(gB0, 32768, 0, 0);
    STAGE(gB0, 32768, 1, 0);
    VMC0();
    BAR();

    #pragma unroll 1
    for (int it = 0; it < KT / 2; ++it) {
        const int kt1 = 2 * it + 1;                               // < KT always
        const int kt2 = (2 * it + 2 < KT) ? 2 * it + 2 : KT - 1;  // clamp: benign restage
        TILE_BODY(0, kt1);
        TILE_BODY(1, kt2);
    }

    // epilogue: nt stores — C write-once, keep L2/L3 for A/B
    const int er = m0 + wr * 128 + (lane >> 4) * 4;
    const int ec = n0 + wc * 64 + (lane & 15);
    #pragma unroll
    for (int ni = 0; ni < 4; ++ni) {
        const float bv = bias[ec + ni * 16];
        #pragma unroll
        for (int mi = 0; mi < 8; ++mi) {
            #pragma unroll
            for (int r = 0; r < 4; ++r) {
                __builtin_nontemporal_store(
                    acc[mi][ni][r] + bv,
                    &C[(long)(er + mi * 16 + r) * OUT_F + ec + ni * 16]);
            }
        }
    }
}

extern "C" void kernel_launch(void* const* d_in, const int* in_sizes, int n_in,
                              void* d_out, int out_size, void* d_ws, size_t ws_size,
                              hipStream_t stream) {
    const float* x    = (const float*)d_in[0];
    const int*   hw   = (const int*)d_in[1];
    const float* hs   = (const float*)d_in[2];
    const int*   lw   = (const int*)d_in[3];
    const float* s1   = (const float*)d_in[4];
    const float* s2   = (const float*)d_in[5];
    const float* zp   = (const float*)d_in[6];
    const int*   cinv = (const int*)d_in[7];
    const float* bias = (const float*)d_in[8];
    float*       out  = (float*)d_out;

    short* wt  = (short*)d_ws;                                     // 90,177,536 B
    short* xb  = (short*)((char*)d_ws + (size_t)OUT_F * IN_F * 2); // +33,554,432 B
    int*   fwd = (int*)((char*)d_ws + (size_t)OUT_F * IN_F * 2
                                    + (size_t)M_TOT * IN_F * 2);   // +44,032 B

    fwd_perm_kernel<<<(OUT_F + 255) / 256, 256, 0, stream>>>(cinv, fwd);
    cvt_x_kernel<<<2048, 256, 0, stream>>>(x, xb);
    dequant_kernel<<<dim3(OUT_F / 64, IN_F / 64), 256, 0, stream>>>(
        hw, hs, lw, s1, s2, zp, fwd, wt);
    gemm_kernel<<<NWG2, 512, 0, stream>>>(xb, wt, bias, out);
}